// Round 1
// baseline (8290.691 us; speedup 1.0000x reference)
//
#include <hip/hip_runtime.h>
#include <stdint.h>

// Dims (fixed by the reference)
#define SS 128   // tokens
#define DD 128   // embed
#define EE 4     // experts
#define HH 8     // heads
#define HDIM 16  // head dim
#define FF 512   // ffn dim
#define BB 512   // batch
#define KK 2     // routed slots
#define NTASK (BB*KK)
#define MAXNF 0.99999f  // 1 - 1e-5

typedef unsigned short u16;
typedef unsigned int u32;

typedef __attribute__((ext_vector_type(8))) short s8v;   // 8 x bf16 (4 VGPRs)
typedef __attribute__((ext_vector_type(4))) float f4v;   // mfma accumulator

#define MFMA32(a,b,c) __builtin_amdgcn_mfma_f32_16x16x32_bf16(a,b,c,0,0,0)

__device__ __forceinline__ float bf2f(u16 h){ return __uint_as_float(((u32)h)<<16); }
__device__ __forceinline__ u16 f2bf(float f){
  u32 x = __float_as_uint(f);
  u32 r = x + 0x7FFFu + ((x>>16)&1u);   // RNE, finite values only
  return (u16)(r>>16);
}
__device__ __forceinline__ float bfl(u32 u){ return __uint_as_float(u<<16); }
__device__ __forceinline__ float bfh(u32 u){ return __uint_as_float(u & 0xFFFF0000u); }
__device__ __forceinline__ u32 packbf(float a, float b){ return (u32)f2bf(a) | ((u32)f2bf(b)<<16); }

__device__ __forceinline__ float wsum(float v){
  #pragma unroll
  for(int off=32; off>0; off>>=1) v += __shfl_xor(v, off, 64);
  return v;
}
__device__ __forceinline__ float wmax(float v){
  #pragma unroll
  for(int off=32; off>0; off>>=1) v = fmaxf(v, __shfl_xor(v, off, 64));
  return v;
}
__device__ __forceinline__ float artanhf_(float x){ return 0.5f*logf((1.f+x)/(1.f-x)); }

// ---- dtype-generic scalar load / store (f32 fallback path) ----
template<typename T> __device__ __forceinline__ float ldv(const T* p){
  if constexpr (sizeof(T)==2) return bf2f(*(const u16*)p);
  else return *(const float*)p;
}
template<typename T> __device__ __forceinline__ void stv(T* p, float v){
  if constexpr (sizeof(T)==2) *(u16*)p = f2bf(v);
  else *(float*)p = v;
}
template<typename T> __device__ __forceinline__ void loadrow(const T* p, float* w){
  if constexpr (sizeof(T)==2){
    const uint4* q=(const uint4*)p;
    #pragma unroll
    for(int r=0;r<16;++r){
      uint4 t=q[r];
      w[r*8+0]=bfl(t.x); w[r*8+1]=bfh(t.x);
      w[r*8+2]=bfl(t.y); w[r*8+3]=bfh(t.y);
      w[r*8+4]=bfl(t.z); w[r*8+5]=bfh(t.z);
      w[r*8+6]=bfl(t.w); w[r*8+7]=bfh(t.w);
    }
  } else {
    const float4* q=(const float4*)p;
    #pragma unroll
    for(int r=0;r<32;++r){ float4 t=q[r]; w[r*4]=t.x; w[r*4+1]=t.y; w[r*4+2]=t.z; w[r*4+3]=t.w; }
  }
}
__device__ __forceinline__ float dotrow(const float* __restrict__ w, const float* __restrict__ u){
  float a0=0.f,a1=0.f,a2=0.f,a3=0.f;
  #pragma unroll
  for(int i=0;i<128;i+=4){
    a0+=w[i]*u[i]; a1+=w[i+1]*u[i+1]; a2+=w[i+2]*u[i+2]; a3+=w[i+3]*u[i+3];
  }
  return (a0+a1)+(a2+a3);
}

// ---- wave-cooperative row ops (row = NPL*64 elems, any lane->elem mapping) ----
template<int NPL> __device__ __forceinline__ float vnorm(const float* v){
  float s=0.f;
  #pragma unroll
  for(int i=0;i<NPL;++i) s += v[i]*v[i];
  s = wsum(s);
  return sqrtf(fmaxf(s, 1e-15f));
}
template<int NPL> __device__ __forceinline__ void f_logmap0(float* v){
  float n = vnorm<NPL>(v);
  float sc = artanhf_(fminf(n, MAXNF))/n;
  #pragma unroll
  for(int i=0;i<NPL;++i) v[i]*=sc;
}
template<int NPL> __device__ __forceinline__ void f_expmap0(float* v){
  float n = vnorm<NPL>(v);
  float sc = tanhf(n)/n;
  #pragma unroll
  for(int i=0;i<NPL;++i) v[i]*=sc;
}
template<int NPL> __device__ __forceinline__ void f_projx(float* v){
  float n = vnorm<NPL>(v);
  if(n > MAXNF){
    float sc = MAXNF/n;
    #pragma unroll
    for(int i=0;i<NPL;++i) v[i]*=sc;
  }
}
template<int NPL> __device__ __forceinline__ void f_mobius_add(float* x, const float* y){
  float xy=0.f, x2=0.f, y2=0.f;
  #pragma unroll
  for(int i=0;i<NPL;++i){ xy+=x[i]*y[i]; x2+=x[i]*x[i]; y2+=y[i]*y[i]; }
  xy=wsum(xy); x2=wsum(x2); y2=wsum(y2);
  float cx = 1.f + 2.f*xy + y2;
  float cy = 1.f - x2;
  float den = fmaxf(1.f + 2.f*xy + x2*y2, 1e-15f);
  float inv = 1.f/den;
  #pragma unroll
  for(int i=0;i<NPL;++i) x[i] = (cx*x[i] + cy*y[i])*inv;
}
template<int NPL> __device__ __forceinline__ void f_layernorm(float* v, const float* g, const float* b){
  const float invD = 1.f/(float)(NPL*64);
  float m=0.f;
  #pragma unroll
  for(int i=0;i<NPL;++i) m += v[i];
  m = wsum(m)*invD;
  float s2=0.f;
  #pragma unroll
  for(int i=0;i<NPL;++i){ v[i]-=m; s2 += v[i]*v[i]; }
  s2 = wsum(s2)*invD;
  float inv = 1.f/sqrtf(s2+1e-5f);
  #pragma unroll
  for(int i=0;i<NPL;++i) v[i] = g[i]*(v[i]*inv) + b[i];
}

// bf16 pair load from global (cols 2l, 2l+1)
__device__ __forceinline__ void ldp(const u16* p, float* v){
  u32 x = *(const u32*)p; v[0]=bfl(x); v[1]=bfh(x);
}

// ---- swizzled LDS tile accessors (bf16 [128][*] tiles, row stride 256B) ----
// byte ^= (row&7)<<4 : MFMA A/B fragment reads (16 rows, same col block) -> <=2-way
__device__ __forceinline__ u32 sw256b(int row, u32 cb){ return (u32)row*256u + (cb ^ (((u32)row&7u)<<4)); }
__device__ __forceinline__ u16* tp16(u16* base, int row, int col){
  return (u16*)((char*)base + sw256b(row, (u32)col*2u));
}
__device__ __forceinline__ u32* tp32(u16* base, int row, int lanepair){
  return (u32*)((char*)base + sw256b(row, (u32)lanepair*4u));
}
__device__ __forceinline__ const s8v* tpv(const u16* base, int row, u32 colbyte){
  return (const s8v*)((const char*)base + sw256b(row, colbyte));
}
// HID tile [64][512] bf16, row stride 1024B, same XOR swizzle
__device__ __forceinline__ u32 hb(int row, u32 cb){ return (u32)row*1024u + (cb ^ (((u32)row&7u)<<4)); }

// ---- prep: wire-dtype detect + mask normalize (unchanged) ----
__global__ void prep_kernel(const u16* __restrict__ feat16,
                            const unsigned char* __restrict__ mask,
                            float* __restrict__ mbias, int* __restrict__ flag){
  __shared__ int s_stats, s_max, s_nan;
  if(threadIdx.x==0){ s_stats=0; s_max=0; s_nan=0; }
  __syncthreads();
  int c=0;
  for(int i=threadIdx.x; i<131072; i+=blockDim.x){
    u16 v = feat16[i];
    if(((v>>7)&0xFFu)==0xFFu) c++;
  }
  if(c) atomicAdd(&s_nan, c);
  int lstats=0, lmax=0;
  for(int i=threadIdx.x; i<BB*SS; i+=blockDim.x){
    int v = mask[i];
    if(v){
      lmax = v>lmax ? v : lmax;
      if((i&3)==1) lstats|=1;
      if((i&3)!=0) lstats|=2;
    }
  }
  if(lstats) atomicOr(&s_stats, lstats);
  atomicMax(&s_max, lmax);
  __syncthreads();
  if(threadIdx.x==0) *flag = (s_nan>0) ? 1 : 0;   // 1 = f32 wire, 0 = bf16 wire
  int mode;
  if(s_max<=1) mode = (s_stats&2) ? 0 : 1;
  else         mode = (s_stats&1) ? 2 : 3;
  for(int i=threadIdx.x; i<BB*SS; i+=blockDim.x){
    bool m2;
    if(mode==0)      m2 = mask[i]!=0;
    else if(mode==1) m2 = ((const int*)mask)[i]!=0;
    else if(mode==2) m2 = ((const u16*)mask)[i]!=0;
    else             m2 = ((((const u32*)mask)[i])<<1)!=0;
    mbias[i] = m2 ? -1e9f : 0.f;
  }
}

template<typename T>
__global__ void zero_nr(const int* __restrict__ flag, const int* __restrict__ eidx, T* __restrict__ out){
  const int want = (sizeof(T)==4) ? 1 : 0;
  if(*flag != want) return;
  for(int slab=blockIdx.x; slab<BB*EE; slab+=gridDim.x){
    int b = slab>>2, e = slab&3;
    if(eidx[b*KK]==e || eidx[b*KK+1]==e) continue;
    T* p = out + (size_t)slab*(SS*DD);
    for(int i=threadIdx.x; i<SS*DD; i+=blockDim.x){
      if constexpr (sizeof(T)==2) p[i] = (T)0; else p[i] = 0.f;
    }
  }
}

// ===================== MFMA bf16 fast path =====================
// LDS layout (144.5 KB, 1 block/CU, 8 waves):
//   UB  [128][128] bf16 sw  : u1 -> P (attn probs) -> u2
//   SF  [32][128]  f32      : matvec raw-out scratch (32-row chunks)
//   KB  [128][128] bf16 sw  : k     ; reused as FR f32 (fc raw) in FFN
//   QB  [128][128] bf16 sw  : q -> ctx -> u_o ; +VTB = HID [64][512] in FFN
//   VTB [128][128] bf16 sw  : v^T (B-operand for PV)
__global__ __launch_bounds__(512)
void moe_mfma(const int* __restrict__ flag,
              const u16* __restrict__ feat, const int* __restrict__ eidx,
              const float* __restrict__ mbias,
              const u16* __restrict__ ln1g, const u16* __restrict__ ln1b,
              const u16* __restrict__ ln2g, const u16* __restrict__ ln2b,
              const u16* __restrict__ wq, const u16* __restrict__ bq,
              const u16* __restrict__ wk, const u16* __restrict__ bk_,
              const u16* __restrict__ wv, const u16* __restrict__ bv,
              const u16* __restrict__ wo, const u16* __restrict__ bo,
              const u16* __restrict__ f1w, const u16* __restrict__ f1b,
              const u16* __restrict__ f2w, const u16* __restrict__ f2b,
              u16* __restrict__ out, float* __restrict__ ws, int ntask)
{
  if(*flag != 0) return;   // bf16 wire only

  __shared__ __align__(16) unsigned char LB[147456];
  __shared__ float mb_s[128];
  u16*   UB  = (u16*)(LB);
  float* SF  = (float*)(LB + 32768);
  u16*   KB  = (u16*)(LB + 49152);
  u16*   QB  = (u16*)(LB + 81920);
  u16*   VTB = (u16*)(LB + 114688);
  float* FR  = (float*)(LB + 49152);         // aliases KB region (32 KB)
  unsigned char* HIDB = LB + 81920;          // aliases QB+VTB (64 KB)

  const int tid  = threadIdx.x;
  const int lane = tid & 63;
  const int w    = tid >> 6;                 // 8 waves
  const int ll   = lane & 15;
  const int hl   = lane >> 4;

  float* gx1 = ws + (size_t)blockIdx.x * (SS*DD);   // f32 x1 residual (64 KB/block)

  for(int task = blockIdx.x; task < ntask; task += gridDim.x){
    __syncthreads();                          // protect LDS across tasks
    const int b = task >> 1;
    const int e = eidx[b*KK + (task & 1)];
    const u16* X = feat + (size_t)task * (SS*DD);

    if(tid < 128) mb_s[tid] = mbias[b*SS + tid];

    // ---- P1: u1 = logmap0(expmap0(LN1(logmap0(x)))) -> UB (bf16, swizzled)
    for(int r=0;r<16;++r){
      int t = w*16 + r;
      float v[2]; ldp(&X[t*DD + 2*lane], v);
      f_logmap0<2>(v);
      float g[2], bb2[2];
      ldp(&ln1g[(size_t)e*DD + 2*lane], g);
      ldp(&ln1b[(size_t)e*DD + 2*lane], bb2);
      f_layernorm<2>(v, g, bb2);
      f_expmap0<2>(v);
      f_logmap0<2>(v);
      *tp32(UB, t, lane) = packbf(v[0], v[1]);
    }
    __syncthreads();

    // ---- P2: q/k/v = logmap0(projx(mobius(expmap0(W@u1), expmap0(b))))
    // MFMA in 32-row chunks (raw f32 -> SF), fused post -> QB / KB / VTB(^T)
    for(int m=0;m<3;++m){
      const u16* Wm = (m==0?wq : m==1?wk : wv) + (size_t)e*DD*DD;
      const u16* Bm = (m==0?bq : m==1?bk_ : bv) + (size_t)e*DD;
      const int n0 = (w>>1)*32;              // wave's 32-col slice
      s8v bfr[4][2];
      #pragma unroll
      for(int ks=0;ks<4;++ks){
        bfr[ks][0] = *(const s8v*)(Wm + (size_t)(n0 + ll)*DD + ks*32 + hl*8);
        bfr[ks][1] = *(const s8v*)(Wm + (size_t)(n0 + 16 + ll)*DD + ks*32 + hl*8);
      }
      for(int ch=0; ch<4; ++ch){
        const int r0 = ch*32 + (w&1)*16;
        f4v a0, a1;
        #pragma unroll
        for(int i=0;i<4;++i){ a0[i]=0.f; a1[i]=0.f; }
        #pragma unroll
        for(int ks=0;ks<4;++ks){
          s8v av = *tpv(UB, r0+ll, (u32)(ks*64 + hl*16));
          a0 = MFMA32(av, bfr[ks][0], a0);
          a1 = MFMA32(av, bfr[ks][1], a1);
        }
        #pragma unroll
        for(int i=0;i<4;++i){
          SF[((w&1)*16 + hl*4 + i)*DD + n0 + ll]      = a0[i];
          SF[((w&1)*16 + hl*4 + i)*DD + n0 + 16 + ll] = a1[i];
        }
        __syncthreads();
        for(int rr=0; rr<4; ++rr){
          int lr = w*4 + rr; int t = ch*32 + lr;
          float v[2]; float2 pp = *(float2*)&SF[lr*DD + 2*lane]; v[0]=pp.x; v[1]=pp.y;
          f_expmap0<2>(v);
          float eb[2]; ldp(&Bm[2*lane], eb); f_expmap0<2>(eb);
          f_mobius_add<2>(v, eb);
          f_projx<2>(v);
          f_logmap0<2>(v);
          if(m==2){
            *tp16(VTB, 2*lane,   t) = f2bf(v[0]);   // V stored transposed
            *tp16(VTB, 2*lane+1, t) = f2bf(v[1]);
          } else {
            u16* tgt = (m==0 ? QB : KB);
            *tp32(tgt, t, lane) = packbf(v[0], v[1]);
          }
        }
        __syncthreads();
      }
    }

    // ---- P3: attention (per head), all wave-local -> no barriers needed
    for(int h=0; h<HH; ++h){
      const int m0 = w*16;                    // wave owns 16 q-rows
      // scores = (Q h-slice) @ (K h-slice)^T via zero-padded K=32 MFMA
      s8v qa;
      #pragma unroll
      for(int i=0;i<8;++i) qa[i]=0;
      if(lane < 32) qa = *tpv(QB, m0+ll, (u32)(h*32 + hl*16));
      f4v sc[8];
      #pragma unroll
      for(int nt=0; nt<8; ++nt){
        s8v kb;
        #pragma unroll
        for(int i=0;i<8;++i) kb[i]=0;
        if(lane < 32) kb = *tpv(KB, nt*16+ll, (u32)(h*32 + hl*16));
        f4v z;
        #pragma unroll
        for(int i=0;i<4;++i) z[i]=0.f;
        sc[nt] = MFMA32(qa, kb, z);
      }
      // softmax over each q-row (row = m0 + hl*4 + i, cols across nt & ll)
      #pragma unroll
      for(int i=0;i<4;++i){
        float s0[8];
        #pragma unroll
        for(int nt=0;nt<8;++nt) s0[nt] = sc[nt][i]*0.25f + mb_s[nt*16 + ll];
        float mx = s0[0];
        #pragma unroll
        for(int nt=1;nt<8;++nt) mx = fmaxf(mx, s0[nt]);
        #pragma unroll
        for(int off=1; off<16; off<<=1) mx = fmaxf(mx, __shfl_xor(mx, off, 64));
        float dn = 0.f;
        #pragma unroll
        for(int nt=0;nt<8;++nt){ s0[nt] = expf(s0[nt]-mx); dn += s0[nt]; }
        #pragma unroll
        for(int off=1; off<16; off<<=1) dn += __shfl_xor(dn, off, 64);
        float inv = 1.f/dn;
        #pragma unroll
        for(int nt=0;nt<8;++nt)
          *tp16(UB, m0 + hl*4 + i, nt*16 + ll) = f2bf(s0[nt]*inv);  // P (wave-own rows)
      }
      // PV: ctx[q, h-slice] = P @ V  (B from V^T tile); overwrite Q h-slice
      f4v ca;
      #pragma unroll
      for(int i=0;i<4;++i) ca[i]=0.f;
      #pragma unroll
      for(int ks=0; ks<4; ++ks){
        s8v pa = *tpv(UB,  m0+ll,    (u32)(ks*64 + hl*16));
        s8v vb = *tpv(VTB, h*16+ll,  (u32)(ks*64 + hl*16));
        ca = MFMA32(pa, vb, ca);
      }
      #pragma unroll
      for(int i=0;i<4;++i)
        *tp16(QB, m0 + hl*4 + i, h*16 + ll) = f2bf(ca[i]);
    }

    // ---- P4a: u_o = logmap0(expmap0(ctx)) in place in QB (wave-own rows)
    for(int r=0;r<16;++r){
      int t = w*16 + r;
      u32 x = *tp32(QB, t, lane);
      float v[2] = { bfl(x), bfh(x) };
      f_expmap0<2>(v);
      f_logmap0<2>(v);
      *tp32(QB, t, lane) = packbf(v[0], v[1]);
    }
    __syncthreads();

    // ---- P4b/P4c: Wo@u_o (chunked MFMA) + attn-out chain, residual, LN2 -> x1(gx1), u2(UB)
    {
      const u16* Wm = wo + (size_t)e*DD*DD;
      const int n0 = (w>>1)*32;
      s8v bfr[4][2];
      #pragma unroll
      for(int ks=0;ks<4;++ks){
        bfr[ks][0] = *(const s8v*)(Wm + (size_t)(n0 + ll)*DD + ks*32 + hl*8);
        bfr[ks][1] = *(const s8v*)(Wm + (size_t)(n0 + 16 + ll)*DD + ks*32 + hl*8);
      }
      for(int ch=0; ch<4; ++ch){
        const int r0 = ch*32 + (w&1)*16;
        f4v a0, a1;
        #pragma unroll
        for(int i=0;i<4;++i){ a0[i]=0.f; a1[i]=0.f; }
        #pragma unroll
        for(int ks=0;ks<4;++ks){
          s8v av = *tpv(QB, r0+ll, (u32)(ks*64 + hl*16));
          a0 = MFMA32(av, bfr[ks][0], a0);
          a1 = MFMA32(av, bfr[ks][1], a1);
        }
        #pragma unroll
        for(int i=0;i<4;++i){
          SF[((w&1)*16 + hl*4 + i)*DD + n0 + ll]      = a0[i];
          SF[((w&1)*16 + hl*4 + i)*DD + n0 + 16 + ll] = a1[i];
        }
        __syncthreads();
        for(int rr=0; rr<4; ++rr){
          int lr = w*4 + rr; int t = ch*32 + lr;
          float v[2]; float2 pp = *(float2*)&SF[lr*DD + 2*lane]; v[0]=pp.x; v[1]=pp.y;
          f_expmap0<2>(v);
          float eb[2]; ldp(&bo[(size_t)e*DD + 2*lane], eb); f_expmap0<2>(eb);
          f_mobius_add<2>(v, eb);
          f_projx<2>(v);              // man_linear's projx
          f_projx<2>(v);              // _expert's projx(_mha(...))
          float res[2]; ldp(&X[t*DD + 2*lane], res);
          f_mobius_add<2>(v, res);
          f_projx<2>(v);              // x1
          float2 xo; xo.x = v[0]; xo.y = v[1];
          *(float2*)&gx1[t*DD + 2*lane] = xo;
          f_logmap0<2>(v);
          float g2[2], b2[2];
          ldp(&ln2g[(size_t)e*DD + 2*lane], g2);
          ldp(&ln2b[(size_t)e*DD + 2*lane], b2);
          f_layernorm<2>(v, g2, b2);
          f_expmap0<2>(v);
          f_projx<2>(v);
          f_logmap0<2>(v);            // u2
          *tp32(UB, t, lane) = packbf(v[0], v[1]);
        }
        __syncthreads();
      }
    }

    // ---- P5: FFN in two 64-token chunks
    for(int tc=0; tc<2; ++tc){
      // fc1: 16-token sub-chunks; raw f32 -> FR[16][512]; post -> HID bf16
      for(int sub=0; sub<4; ++sub){
        const int t0 = tc*64 + sub*16;
        f4v fa[4];
        #pragma unroll
        for(int nt=0;nt<4;++nt)
          #pragma unroll
          for(int i=0;i<4;++i) fa[nt][i]=0.f;
        #pragma unroll
        for(int ks=0; ks<4; ++ks){
          s8v av = *tpv(UB, t0+ll, (u32)(ks*64 + hl*16));
          #pragma unroll
          for(int nt=0; nt<4; ++nt){
            s8v bb = *(const s8v*)(f1w + (size_t)e*FF*DD + (size_t)(w*64 + nt*16 + ll)*DD + ks*32 + hl*8);
            fa[nt] = MFMA32(av, bb, fa[nt]);
          }
        }
        #pragma unroll
        for(int nt=0;nt<4;++nt)
          #pragma unroll
          for(int i=0;i<4;++i)
            FR[(hl*4+i)*FF + w*64 + nt*16 + ll] = fa[nt][i];
        __syncthreads();
        for(int rr=0; rr<2; ++rr){
          int lr = w*2 + rr;
          int hrow = sub*16 + lr;
          float v[8];
          #pragma unroll
          for(int j=0;j<4;++j){
            float2 pp = *(float2*)&FR[lr*FF + 2*lane + 128*j];
            v[2*j]=pp.x; v[2*j+1]=pp.y;
          }
          f_expmap0<8>(v);
          float eb[8];
          #pragma unroll
          for(int j=0;j<4;++j) ldp(&f1b[(size_t)e*FF + 2*lane + 128*j], &eb[2*j]);
          f_expmap0<8>(eb);
          f_mobius_add<8>(v, eb);
          f_projx<8>(v);            // man_linear projx
          f_logmap0<8>(v);
          #pragma unroll
          for(int i=0;i<8;++i) v[i] = fmaxf(v[i], 0.f);
          f_expmap0<8>(v);          // mob_relu
          f_projx<8>(v);            // h = projx(...)
          f_logmap0<8>(v);          // u3
          #pragma unroll
          for(int j=0;j<4;++j)
            *(u32*)(HIDB + hb(hrow, (u32)(4*lane + 256*j))) = packbf(v[2*j], v[2*j+1]);
        }
        __syncthreads();
      }
      // fc2: [64 tok] x [512] @ W^T -> raw f32 FR[64][128]; post + residual + store
      {
        const int r0 = (w&3)*16;
        const int n0 = (w>>2)*64;
        f4v ga[4];
        #pragma unroll
        for(int nt=0;nt<4;++nt)
          #pragma unroll
          for(int i=0;i<4;++i) ga[nt][i]=0.f;
        #pragma unroll
        for(int ks=0; ks<16; ++ks){
          s8v av = *(const s8v*)(HIDB + hb(r0+ll, (u32)(ks*64 + hl*16)));
          #pragma unroll
          for(int nt=0; nt<4; ++nt){
            s8v bb = *(const s8v*)(f2w + (size_t)e*DD*FF + (size_t)(n0 + nt*16 + ll)*FF + ks*32 + hl*8);
            ga[nt] = MFMA32(av, bb, ga[nt]);
          }
        }
        #pragma unroll
        for(int nt=0;nt<4;++nt)
          #pragma unroll
          for(int i=0;i<4;++i)
            FR[(r0 + hl*4 + i)*DD + n0 + nt*16 + ll] = ga[nt][i];
        __syncthreads();
        for(int rr=0; rr<8; ++rr){
          int lr = w*8 + rr; int gt = tc*64 + lr;
          float v[2]; float2 pp = *(float2*)&FR[lr*DD + 2*lane]; v[0]=pp.x; v[1]=pp.y;
          f_expmap0<2>(v);
          float eb[2]; ldp(&f2b[(size_t)e*DD + 2*lane], eb); f_expmap0<2>(eb);
          f_mobius_add<2>(v, eb);
          f_projx<2>(v);            // man_linear projx
          f_logmap0<2>(v);
          v[0]=fmaxf(v[0],0.f); v[1]=fmaxf(v[1],0.f);
          f_expmap0<2>(v);          // mob_relu (no projx per reference)
          float x1v[2]; float2 xx = *(float2*)&gx1[gt*DD + 2*lane]; x1v[0]=xx.x; x1v[1]=xx.y;
          f_mobius_add<2>(v, x1v);
          f_projx<2>(v);
          u16* op = out + ((size_t)(b*EE+e)*SS + gt)*DD;
          *(u32*)&op[2*lane] = packbf(v[0], v[1]);
        }
        __syncthreads();
      }
    }
  }
}

// ===================== f32-wire fallback (previous verified kernel) =====================
template<typename T>
__global__ __launch_bounds__(256)
void moe_kernel(const int* __restrict__ flag,
                const T* __restrict__ feat, const int* __restrict__ eidx,
                const float* __restrict__ mbias,
                const T* __restrict__ ln1g, const T* __restrict__ ln1b,
                const T* __restrict__ ln2g, const T* __restrict__ ln2b,
                const T* __restrict__ wq, const T* __restrict__ bq,
                const T* __restrict__ wk, const T* __restrict__ bk_,
                const T* __restrict__ wv, const T* __restrict__ bv,
                const T* __restrict__ wo, const T* __restrict__ bo,
                const T* __restrict__ f1w, const T* __restrict__ f1b,
                const T* __restrict__ f2w, const T* __restrict__ f2b,
                T* __restrict__ out, float* __restrict__ ws, int ntask)
{
  const int want = (sizeof(T)==4) ? 1 : 0;
  if(*flag != want) return;

  __shared__ float U[SS*DD];
  const int tid  = threadIdx.x;
  const int lane = tid & 63;
  const int wid  = tid >> 6;
  float* T0 = ws + (size_t)blockIdx.x * (4*SS*DD);
  float* T1 = T0 + SS*DD;
  float* T2 = T1 + SS*DD;
  float* T3 = T2 + SS*DD;

  for(int task = blockIdx.x; task < ntask; task += gridDim.x){
    __syncthreads();
    const int b = task >> 1;
    const int e = eidx[b*KK + (task & 1)];
    const T* X = feat + (size_t)task * (SS*DD);

    for(int r=0;r<32;++r){
      int t = wid*32 + r;
      float v[2];
      v[0]=ldv(&X[t*DD+lane]); v[1]=ldv(&X[t*DD+lane+64]);
      f_logmap0<2>(v);
      float g[2], bb[2];
      g[0]=ldv(&ln1g[e*DD+lane]);  g[1]=ldv(&ln1g[e*DD+lane+64]);
      bb[0]=ldv(&ln1b[e*DD+lane]); bb[1]=ldv(&ln1b[e*DD+lane+64]);
      f_layernorm<2>(v,g,bb);
      f_expmap0<2>(v);
      f_logmap0<2>(v);
      U[t*DD+lane]=v[0]; U[t*DD+lane+64]=v[1];
    }
    __syncthreads();

    {
      int j = tid & 127, tg = tid >> 7;
      for(int m=0;m<3;++m){
        const T* Wm = (m==0?wq : m==1?wk : wv) + (size_t)e*DD*DD + (size_t)j*DD;
        float* Ym = (m==0?T0 : m==1?T1 : T2);
        float w[128];
        loadrow(Wm, w);
        for(int tt=0;tt<64;++tt){
          int t = tg*64+tt;
          Ym[t*DD+j] = dotrow(w, &U[t*DD]);
        }
      }
    }
    __syncthreads();

    for(int m=0;m<3;++m){
      const T* bias = (m==0?bq : m==1?bk_ : bv) + e*DD;
      float* Y = (m==0?T0 : m==1?T1 : T2);
      for(int r=0;r<32;++r){
        int t = wid*32+r;
        float v[2]; v[0]=Y[t*DD+lane]; v[1]=Y[t*DD+lane+64];
        f_expmap0<2>(v);
        float ebv[2]; ebv[0]=ldv(&bias[lane]); ebv[1]=ldv(&bias[lane+64]);
        f_expmap0<2>(ebv);
        f_mobius_add<2>(v, ebv);
        f_projx<2>(v);
        f_logmap0<2>(v);
        Y[t*DD+lane]=v[0]; Y[t*DD+lane+64]=v[1];
      }
    }
    __syncthreads();

    {
      const float* mb = mbias + b*SS;
      for(int h=0; h<HH; ++h){
        for(int r=0;r<32;++r){
          int t = wid*32+r;
          float q16[16];
          #pragma unroll
          for(int i=0;i<16;++i) q16[i] = T0[t*DD + h*HDIM + i];
          int k0 = lane, k1 = lane+64;
          float s0=0.f, s1=0.f;
          #pragma unroll
          for(int i=0;i<16;++i){
            s0 += q16[i]*T1[k0*DD + h*HDIM + i];
            s1 += q16[i]*T1[k1*DD + h*HDIM + i];
          }
          s0 = s0*0.25f + mb[k0];
          s1 = s1*0.25f + mb[k1];
          float mx = wmax(fmaxf(s0,s1));
          float p0 = expf(s0-mx), p1 = expf(s1-mx);
          float dn = wsum(p0+p1);
          p0 /= dn; p1 /= dn;
          float part[16];
          #pragma unroll
          for(int i=0;i<16;++i)
            part[i] = p0*T2[k0*DD+h*HDIM+i] + p1*T2[k1*DD+h*HDIM+i];
          #pragma unroll
          for(int off=1; off<64; off<<=1){
            #pragma unroll
            for(int i=0;i<16;++i) part[i] += __shfl_xor(part[i], off, 64);
          }
          if(lane==0){
            #pragma unroll
            for(int i=0;i<16;++i) T0[t*DD + h*HDIM + i] = part[i];
          }
        }
      }
    }
    __syncthreads();

    for(int r=0;r<32;++r){
      int t=wid*32+r;
      float v[2]; v[0]=T0[t*DD+lane]; v[1]=T0[t*DD+lane+64];
      f_expmap0<2>(v);
      f_logmap0<2>(v);
      U[t*DD+lane]=v[0]; U[t*DD+lane+64]=v[1];
    }
    __syncthreads();

    {
      int j=tid&127, tg=tid>>7;
      float w[128];
      loadrow(wo + (size_t)e*DD*DD + (size_t)j*DD, w);
      for(int tt=0;tt<64;++tt){
        int t=tg*64+tt;
        T1[t*DD+j] = dotrow(w, &U[t*DD]);
      }
    }
    __syncthreads();

    for(int r=0;r<32;++r){
      int t=wid*32+r;
      float v[2]; v[0]=T1[t*DD+lane]; v[1]=T1[t*DD+lane+64];
      f_expmap0<2>(v);
      float ebv[2]; ebv[0]=ldv(&bo[e*DD+lane]); ebv[1]=ldv(&bo[e*DD+lane+64]);
      f_expmap0<2>(ebv);
      f_mobius_add<2>(v, ebv);
      f_projx<2>(v);
      f_projx<2>(v);
      float res[2]; res[0]=ldv(&X[t*DD+lane]); res[1]=ldv(&X[t*DD+lane+64]);
      f_mobius_add<2>(v, res);
      f_projx<2>(v);
      T3[t*DD+lane]=v[0]; T3[t*DD+lane+64]=v[1];
      f_logmap0<2>(v);
      float g2[2], b2[2];
      g2[0]=ldv(&ln2g[e*DD+lane]); g2[1]=ldv(&ln2g[e*DD+lane+64]);
      b2[0]=ldv(&ln2b[e*DD+lane]); b2[1]=ldv(&ln2b[e*DD+lane+64]);
      f_layernorm<2>(v,g2,b2);
      f_expmap0<2>(v);
      f_projx<2>(v);
      f_logmap0<2>(v);
      U[t*DD+lane]=v[0]; U[t*DD+lane+64]=v[1];
    }
    __syncthreads();

    float* HID = T0;
    for(int tc=0; tc<2; ++tc){
      for(int pass=0;pass<2;++pass){
        int f = pass*256 + tid;
        float w[128];
        loadrow(f1w + (size_t)e*FF*DD + (size_t)f*DD, w);
        for(int tt=0;tt<64;++tt){
          HID[tt*FF+f] = dotrow(w, &U[(tc*64+tt)*DD]);
        }
      }
      __syncthreads();
      for(int r=0;r<16;++r){
        int t = wid*16+r;
        float v[8];
        #pragma unroll
        for(int i=0;i<8;++i) v[i]=HID[t*FF+lane+64*i];
        f_expmap0<8>(v);
        float ebv[8];
        #pragma unroll
        for(int i=0;i<8;++i) ebv[i]=ldv(&f1b[e*FF+lane+64*i]);
        f_expmap0<8>(ebv);
        f_mobius_add<8>(v, ebv);
        f_projx<8>(v);
        f_logmap0<8>(v);
        #pragma unroll
        for(int i=0;i<8;++i) v[i]=fmaxf(v[i],0.f);
        f_expmap0<8>(v);
        f_projx<8>(v);
        f_logmap0<8>(v);
        #pragma unroll
        for(int i=0;i<8;++i) HID[t*FF+lane+64*i]=v[i];
      }
      __syncthreads();
      {
        int j=tid&127, tg=tid>>7;
        for(int fc=0;fc<4;++fc){
          float w[128];
          loadrow(f2w + (size_t)e*DD*FF + (size_t)j*FF + fc*128, w);
          for(int tt=0;tt<32;++tt){
            int t=tg*32+tt;
            float acc = dotrow(w, HID + t*FF + fc*128);
            if(fc==0) T2[t*DD+j]=acc; else T2[t*DD+j]+=acc;
          }
        }
      }
      __syncthreads();
      for(int r=0;r<16;++r){
        int t=wid*16+r; int gt = tc*64+t;
        float v[2]; v[0]=T2[t*DD+lane]; v[1]=T2[t*DD+lane+64];
        f_expmap0<2>(v);
        float ebv[2]; ebv[0]=ldv(&f2b[e*DD+lane]); ebv[1]=ldv(&f2b[e*DD+lane+64]);
        f_expmap0<2>(ebv);
        f_mobius_add<2>(v, ebv);
        f_projx<2>(v);
        f_logmap0<2>(v);
        v[0]=fmaxf(v[0],0.f); v[1]=fmaxf(v[1],0.f);
        f_expmap0<2>(v);
        float x1v[2]; x1v[0]=T3[gt*DD+lane]; x1v[1]=T3[gt*DD+lane+64];
        f_mobius_add<2>(v, x1v);
        f_projx<2>(v);
        T* op = out + ((size_t)(b*EE+e)*SS + gt)*DD;
        stv(&op[lane],    v[0]);
        stv(&op[lane+64], v[1]);
      }
      __syncthreads();
    }
  }
}

extern "C" void kernel_launch(void* const* d_in, const int* in_sizes, int n_in,
                              void* d_out, int out_size, void* d_ws, size_t ws_size,
                              hipStream_t stream){
  const void* feat = d_in[0];
  const int* eidx = (const int*)d_in[1];
  const unsigned char* pmask = (const unsigned char*)d_in[2];
  float* ws = (float*)d_ws;

  // ws layout: [0..15] flag, [16 .. 16+BB*SS) mbias, then per-block tiles
  int* flag = (int*)ws;
  float* mbias = ws + 16;
  float* tiles = ws + 16 + BB*SS;
  long avail = (long)(ws_size/sizeof(float)) - (16 + BB*SS);

  // f32 fallback grid (4 tiles/block)
  const size_t blkF = 4*SS*DD;
  int G = (int)(avail / (long)blkF);
  if(G > NTASK) G = NTASK;
  if(G < 1) G = 1;
  // bf16 MFMA grid (1 f32 x1 tile/block)
  const size_t blkM = SS*DD;
  int GM = (int)(avail / (long)blkM);
  if(GM > NTASK) GM = NTASK;
  if(GM < 1) GM = 1;

  prep_kernel<<<1,256,0,stream>>>((const u16*)feat, pmask, mbias, flag);
  zero_nr<u16>  <<<2048,256,0,stream>>>(flag, eidx, (u16*)d_out);
  zero_nr<float><<<2048,256,0,stream>>>(flag, eidx, (float*)d_out);

  moe_mfma<<<GM,512,0,stream>>>(flag, (const u16*)d_in[0], eidx, mbias,
    (const u16*)d_in[3], (const u16*)d_in[4], (const u16*)d_in[5], (const u16*)d_in[6],
    (const u16*)d_in[7], (const u16*)d_in[8], (const u16*)d_in[9], (const u16*)d_in[10],
    (const u16*)d_in[11], (const u16*)d_in[12], (const u16*)d_in[13], (const u16*)d_in[14],
    (const u16*)d_in[15], (const u16*)d_in[16], (const u16*)d_in[17], (const u16*)d_in[18],
    (u16*)d_out, tiles, NTASK);

  #define ARGS(T_) flag, (const T_*)d_in[0], eidx, mbias, \
    (const T_*)d_in[3], (const T_*)d_in[4], (const T_*)d_in[5], (const T_*)d_in[6], \
    (const T_*)d_in[7], (const T_*)d_in[8], (const T_*)d_in[9], (const T_*)d_in[10], \
    (const T_*)d_in[11], (const T_*)d_in[12], (const T_*)d_in[13], (const T_*)d_in[14], \
    (const T_*)d_in[15], (const T_*)d_in[16], (const T_*)d_in[17], (const T_*)d_in[18], \
    (T_*)d_out, tiles, NTASK
  moe_kernel<float><<<G,256,0,stream>>>(ARGS(float));
  #undef ARGS
}

// Round 2
// 4288.613 us; speedup vs baseline: 1.9332x; 1.9332x over previous
//
#include <hip/hip_runtime.h>
#include <stdint.h>

// Dims (fixed by the reference)
#define SS 128   // tokens
#define DD 128   // embed
#define EE 4     // experts
#define HH 8     // heads
#define HDIM 16  // head dim
#define FF 512   // ffn dim
#define BB 512   // batch
#define KK 2     // routed slots
#define NTASK (BB*KK)
#define MAXNF 0.99999f  // 1 - 1e-5
#define NW3 786432      // elems per split-weight plane

typedef unsigned short u16;
typedef unsigned int u32;

typedef __attribute__((ext_vector_type(8))) short s8v;   // 8 x bf16 (4 VGPRs)
typedef __attribute__((ext_vector_type(4))) float f4v;   // mfma accumulator

#define MFMA32(a,b,c) __builtin_amdgcn_mfma_f32_16x16x32_bf16(a,b,c,0,0,0)

__device__ __forceinline__ float bf2f(u16 h){ return __uint_as_float(((u32)h)<<16); }
__device__ __forceinline__ u16 f2bf(float f){
  u32 x = __float_as_uint(f);
  u32 r = x + 0x7FFFu + ((x>>16)&1u);   // RNE, finite values only
  return (u16)(r>>16);
}
__device__ __forceinline__ float bfl(u32 u){ return __uint_as_float(u<<16); }
__device__ __forceinline__ float bfh(u32 u){ return __uint_as_float(u & 0xFFFF0000u); }

__device__ __forceinline__ float wsum(float v){
  #pragma unroll
  for(int off=32; off>0; off>>=1) v += __shfl_xor(v, off, 64);
  return v;
}
__device__ __forceinline__ float wmax(float v){
  #pragma unroll
  for(int off=32; off>0; off>>=1) v = fmaxf(v, __shfl_xor(v, off, 64));
  return v;
}
__device__ __forceinline__ float artanhf_(float x){ return 0.5f*logf((1.f+x)/(1.f-x)); }

// pack 2 f32 -> 2 bf16 (RNE), low word = a
__device__ __forceinline__ u32 cvtpk(float a, float b){
  u32 r; asm("v_cvt_pk_bf16_f32 %0, %1, %2" : "=v"(r) : "v"(a), "v"(b)); return r;
}
// 3-level split of a pair: h+m+l ~= x to ~2^-24 rel
__device__ __forceinline__ void split2(float a, float b, u32& H, u32& M, u32& L){
  H = cvtpk(a,b);
  float ra = a - bfl(H), rb = b - bfh(H);
  M = cvtpk(ra,rb);
  float sa = ra - bfl(M), sb = rb - bfh(M);
  L = cvtpk(sa,sb);
}
__device__ __forceinline__ void split8(const float* v, s8v& H, s8v& M, s8v& L){
  union { u32 w[4]; s8v s; } uh, um, ul;
  #pragma unroll
  for(int p=0;p<4;++p){
    u32 a,bq2,c; split2(v[2*p], v[2*p+1], a, bq2, c);
    uh.w[p]=a; um.w[p]=bq2; ul.w[p]=c;
  }
  H=uh.s; M=um.s; L=ul.s;
}
__device__ __forceinline__ s8v sel8(int c, s8v a, s8v b){ return c ? a : b; }

// ---- dtype-generic scalar load / store (fallback path) ----
template<typename T> __device__ __forceinline__ float ldv(const T* p){
  if constexpr (sizeof(T)==2) return bf2f(*(const u16*)p);
  else return *(const float*)p;
}
template<typename T> __device__ __forceinline__ void stv(T* p, float v){
  if constexpr (sizeof(T)==2) *(u16*)p = f2bf(v);
  else *(float*)p = v;
}
template<typename T> __device__ __forceinline__ void loadrow(const T* p, float* w){
  if constexpr (sizeof(T)==2){
    const uint4* q=(const uint4*)p;
    #pragma unroll
    for(int r=0;r<16;++r){
      uint4 t=q[r];
      w[r*8+0]=bfl(t.x); w[r*8+1]=bfh(t.x);
      w[r*8+2]=bfl(t.y); w[r*8+3]=bfh(t.y);
      w[r*8+4]=bfl(t.z); w[r*8+5]=bfh(t.z);
      w[r*8+6]=bfl(t.w); w[r*8+7]=bfh(t.w);
    }
  } else {
    const float4* q=(const float4*)p;
    #pragma unroll
    for(int r=0;r<32;++r){ float4 t=q[r]; w[r*4]=t.x; w[r*4+1]=t.y; w[r*4+2]=t.z; w[r*4+3]=t.w; }
  }
}
__device__ __forceinline__ float dotrow(const float* __restrict__ w, const float* __restrict__ u){
  float a0=0.f,a1=0.f,a2=0.f,a3=0.f;
  #pragma unroll
  for(int i=0;i<128;i+=4){
    a0+=w[i]*u[i]; a1+=w[i+1]*u[i+1]; a2+=w[i+2]*u[i+2]; a3+=w[i+3]*u[i+3];
  }
  return (a0+a1)+(a2+a3);
}

// ---- wave-cooperative row ops (row = NPL*64 elems, any lane->elem mapping) ----
template<int NPL> __device__ __forceinline__ float vnorm(const float* v){
  float s=0.f;
  #pragma unroll
  for(int i=0;i<NPL;++i) s += v[i]*v[i];
  s = wsum(s);
  return sqrtf(fmaxf(s, 1e-15f));
}
template<int NPL> __device__ __forceinline__ void f_logmap0(float* v){
  float n = vnorm<NPL>(v);
  float sc = artanhf_(fminf(n, MAXNF))/n;
  #pragma unroll
  for(int i=0;i<NPL;++i) v[i]*=sc;
}
template<int NPL> __device__ __forceinline__ void f_expmap0(float* v){
  float n = vnorm<NPL>(v);
  float sc = tanhf(n)/n;
  #pragma unroll
  for(int i=0;i<NPL;++i) v[i]*=sc;
}
template<int NPL> __device__ __forceinline__ void f_projx(float* v){
  float n = vnorm<NPL>(v);
  if(n > MAXNF){
    float sc = MAXNF/n;
    #pragma unroll
    for(int i=0;i<NPL;++i) v[i]*=sc;
  }
}
template<int NPL> __device__ __forceinline__ void f_mobius_add(float* x, const float* y){
  float xy=0.f, x2=0.f, y2=0.f;
  #pragma unroll
  for(int i=0;i<NPL;++i){ xy+=x[i]*y[i]; x2+=x[i]*x[i]; y2+=y[i]*y[i]; }
  xy=wsum(xy); x2=wsum(x2); y2=wsum(y2);
  float cx = 1.f + 2.f*xy + y2;
  float cy = 1.f - x2;
  float den = fmaxf(1.f + 2.f*xy + x2*y2, 1e-15f);
  float inv = 1.f/den;
  #pragma unroll
  for(int i=0;i<NPL;++i) x[i] = (cx*x[i] + cy*y[i])*inv;
}
template<int NPL> __device__ __forceinline__ void f_layernorm(float* v, const float* g, const float* b){
  const float invD = 1.f/(float)(NPL*64);
  float m=0.f;
  #pragma unroll
  for(int i=0;i<NPL;++i) m += v[i];
  m = wsum(m)*invD;
  float s2=0.f;
  #pragma unroll
  for(int i=0;i<NPL;++i){ v[i]-=m; s2 += v[i]*v[i]; }
  s2 = wsum(s2)*invD;
  float inv = 1.f/sqrtf(s2+1e-5f);
  #pragma unroll
  for(int i=0;i<NPL;++i) v[i] = g[i]*(v[i]*inv) + b[i];
}

// ---- XOR-swizzled LDS addressing (16B granule) ----
__device__ __forceinline__ u32 xf32(int row, int colf){ // f32 tile, stride 512B
  return (u32)row*512u + (((u32)colf*4u) ^ (((u32)row&7u)<<4));
}
__device__ __forceinline__ u32 xbh(int row, int colb){ // bf16 tile [128][128], stride 256B
  return (u32)row*256u + (((u32)colb*2u) ^ (((u32)row&7u)<<4));
}
__device__ __forceinline__ u32 xhid(int row, int colb){ // bf16 [16][512], stride 1024B
  return (u32)row*1024u + (((u32)colb*2u) ^ (((u32)row&7u)<<4));
}
__device__ __forceinline__ u32 xfr_(int row, int colf){ // f32 [16][512], stride 2048B
  return (u32)row*2048u + (((u32)colf*4u) ^ (((u32)row&7u)<<4));
}

// ---- prep: wire-dtype detect + mask normalize ----
__global__ void prep_kernel(const u16* __restrict__ feat16,
                            const unsigned char* __restrict__ mask,
                            float* __restrict__ mbias, int* __restrict__ flag){
  __shared__ int s_stats, s_max, s_nan;
  if(threadIdx.x==0){ s_stats=0; s_max=0; s_nan=0; }
  __syncthreads();
  int c=0;
  for(int i=threadIdx.x; i<131072; i+=blockDim.x){
    u16 v = feat16[i];
    if(((v>>7)&0xFFu)==0xFFu) c++;
  }
  if(c) atomicAdd(&s_nan, c);
  int lstats=0, lmax=0;
  for(int i=threadIdx.x; i<BB*SS; i+=blockDim.x){
    int v = mask[i];
    if(v){
      lmax = v>lmax ? v : lmax;
      if((i&3)==1) lstats|=1;
      if((i&3)!=0) lstats|=2;
    }
  }
  if(lstats) atomicOr(&s_stats, lstats);
  atomicMax(&s_max, lmax);
  __syncthreads();
  if(threadIdx.x==0) *flag = (s_nan>0) ? 1 : 0;   // 1 = f32 wire, 0 = bf16 wire
  int mode;
  if(s_max<=1) mode = (s_stats&2) ? 0 : 1;
  else         mode = (s_stats&1) ? 2 : 3;
  for(int i=threadIdx.x; i<BB*SS; i+=blockDim.x){
    bool m2;
    if(mode==0)      m2 = mask[i]!=0;
    else if(mode==1) m2 = ((const int*)mask)[i]!=0;
    else if(mode==2) m2 = ((const u16*)mask)[i]!=0;
    else             m2 = ((((const u32*)mask)[i])<<1)!=0;
    mbias[i] = m2 ? -1e9f : 0.f;
  }
}

template<typename T>
__global__ void zero_nr(const int* __restrict__ flag, const int* __restrict__ eidx, T* __restrict__ out){
  const int want = (sizeof(T)==4) ? 1 : 0;
  if(*flag != want) return;
  for(int slab=blockIdx.x; slab<BB*EE; slab+=gridDim.x){
    int b = slab>>2, e = slab&3;
    if(eidx[b*KK]==e || eidx[b*KK+1]==e) continue;
    T* p = out + (size_t)slab*(SS*DD);
    for(int i=threadIdx.x; i<SS*DD; i+=blockDim.x){
      if constexpr (sizeof(T)==2) p[i] = (T)0; else p[i] = 0.f;
    }
  }
}

// ---- pre-split weights into 3 bf16 planes (h/m/l) in workspace ----
__global__ void wsplit_kernel(const int* __restrict__ flag,
                              const float* __restrict__ wq, const float* __restrict__ wk,
                              const float* __restrict__ wv, const float* __restrict__ wo,
                              const float* __restrict__ f1w, const float* __restrict__ f2w,
                              u16* __restrict__ wsp){
  if(*flag != 1) return;
  int i = blockIdx.x*256 + threadIdx.x;
  if(i >= NW3) return;
  float x;
  if(i < 65536)       x = wq[i];
  else if(i < 131072) x = wk[i-65536];
  else if(i < 196608) x = wv[i-131072];
  else if(i < 262144) x = wo[i-196608];
  else if(i < 524288) x = f1w[i-262144];
  else                x = f2w[i-524288];
  u32 H,M,L; split2(x,x,H,M,L);
  wsp[i]         = (u16)H;
  wsp[NW3 + i]   = (u16)M;
  wsp[2*NW3 + i] = (u16)L;
}

// ===================== f32-wire MFMA kernel =====================
// LDS (160KB): Uh[0,32K) Um[32K,64K) bf16 planar (u1->u_o->u2; f32 P tile during attn over [0,64K))
//              R2[64K,128K) f32 tile (K -> ctx -> FR/HID3-head)
//              SX[128K,160K): C-staging SF[32][128] / K head-slice 3c / HID3 tail + fc2raw
// out-slab scratch: spare slab = Q f32 (re-zeroed), own slab = V^T f32 -> x1 f32 -> final out
// ws: per-block l-plane of U (32KB)
__global__ __launch_bounds__(512)
void moe_f32(const int* __restrict__ flag,
             const float* __restrict__ feat, const int* __restrict__ eidx,
             const float* __restrict__ mbias,
             const float* __restrict__ ln1g, const float* __restrict__ ln1b,
             const float* __restrict__ ln2g, const float* __restrict__ ln2b,
             const float* __restrict__ bq, const float* __restrict__ bk_,
             const float* __restrict__ bv, const float* __restrict__ bo,
             const float* __restrict__ f1b, const float* __restrict__ f2b,
             const u16* __restrict__ wsp,
             float* __restrict__ out, float* __restrict__ wsl, int ntask)
{
  if(*flag != 1) return;

  __shared__ __align__(16) char LB[163840];
  char* Uh = LB;
  char* Um = LB + 32768;
  char* R2 = LB + 65536;
  char* SX = LB + 131072;
  char* HB = LB + 98304;           // HID3 [3][16][512] bf16 (49152B, spans R2-upper + SX-low)
  char* C2 = LB + 147456;          // fc2 raw [16][128] f32 (8KB)

  const int tid = threadIdx.x;
  const int lane = tid & 63;
  const int w    = tid >> 6;       // 8 waves
  const int ll   = lane & 15;
  const int hl   = lane >> 4;

  u16* myl = (u16*)wsl + (size_t)blockIdx.x * 16384;   // u l-plane [128][128] bf16 (linear)

  for(int task = blockIdx.x; task < ntask; task += gridDim.x){
    __syncthreads();
    const int b = task >> 1, slot = task & 1;
    const int e  = eidx[b*KK + slot];
    const int eo = eidx[b*KK + (slot^1)];
    int used = (1<<e)|(1<<eo), sp = 0, cnt = 0;
    #pragma unroll
    for(int t2=0;t2<4;++t2){ if(!((used>>t2)&1)){ if(cnt==slot) sp=t2; cnt++; } }
    const float* X = feat + (size_t)task * (SS*DD);
    float* own   = out + ((size_t)(b*EE+e )) * (SS*DD);
    float* spare = out + ((size_t)(b*EE+sp)) * (SS*DD);

    // hoisted per-task row params (lane holds cols 2*lane, 2*lane+1)
    float g1[2],b1[2],g2[2],b2[2],ebq[2],ebk[2],ebv[2],ebo[2],ebf2[2],ebf1[8];
    {
      float2 t0;
      t0 = *(const float2*)(ln1g + e*DD + 2*lane); g1[0]=t0.x; g1[1]=t0.y;
      t0 = *(const float2*)(ln1b + e*DD + 2*lane); b1[0]=t0.x; b1[1]=t0.y;
      t0 = *(const float2*)(ln2g + e*DD + 2*lane); g2[0]=t0.x; g2[1]=t0.y;
      t0 = *(const float2*)(ln2b + e*DD + 2*lane); b2[0]=t0.x; b2[1]=t0.y;
      t0 = *(const float2*)(bq  + e*DD + 2*lane); ebq[0]=t0.x; ebq[1]=t0.y; f_expmap0<2>(ebq);
      t0 = *(const float2*)(bk_ + e*DD + 2*lane); ebk[0]=t0.x; ebk[1]=t0.y; f_expmap0<2>(ebk);
      t0 = *(const float2*)(bv  + e*DD + 2*lane); ebv[0]=t0.x; ebv[1]=t0.y; f_expmap0<2>(ebv);
      t0 = *(const float2*)(bo  + e*DD + 2*lane); ebo[0]=t0.x; ebo[1]=t0.y; f_expmap0<2>(ebo);
      t0 = *(const float2*)(f2b + e*DD + 2*lane); ebf2[0]=t0.x; ebf2[1]=t0.y; f_expmap0<2>(ebf2);
      #pragma unroll
      for(int j=0;j<4;++j){
        t0 = *(const float2*)(f1b + e*FF + 2*lane + 128*j); ebf1[2*j]=t0.x; ebf1[2*j+1]=t0.y;
      }
      f_expmap0<8>(ebf1);
    }
    float mb_reg[8];
    #pragma unroll
    for(int nt=0;nt<8;++nt) mb_reg[nt] = mbias[b*SS + nt*16 + ll];

    // ---- P1: u1 = logmap0(expmap0(LN1(logmap0(x)))) -> Uh/Um/myl (3c)
    for(int r=0;r<16;++r){
      int t = w*16 + r;
      float2 xv = *(const float2*)(X + t*DD + 2*lane);
      float v[2] = {xv.x, xv.y};
      f_logmap0<2>(v);
      f_layernorm<2>(v, g1, b1);
      f_expmap0<2>(v);
      f_logmap0<2>(v);
      u32 H,M,L; split2(v[0],v[1],H,M,L);
      *(u32*)(Uh + xbh(t, 2*lane)) = H;
      *(u32*)(Um + xbh(t, 2*lane)) = M;
      ((u32*)myl)[t*64 + lane] = L;
    }
    __syncthreads();

    // ---- P2: q/k/v matvecs (3c MFMA) + fused post -> spare(q f32) / R2(k f32) / own(v^T f32)
    #pragma unroll
    for(int m=0;m<3;++m){
      const u32 tb = (m==0 ? 0u : (m==1 ? 65536u : 131072u)) + (u32)e*16384u;
      s8v Bh[8], Blm[8];
      {
        int nrow = w*16 + ll;
        #pragma unroll
        for(int c=0;c<8;++c){
          u32 koff = c*16 + (hl&1)*8;
          Bh[c]  = *(const s8v*)(wsp + 0*NW3 + tb + nrow*128 + koff);
          Blm[c] = *(const s8v*)(wsp + (hl<2?2:1)*NW3 + tb + nrow*128 + koff);
        }
      }
      for(int ch=0; ch<4; ++ch){
        #pragma unroll
        for(int sub=0; sub<2; ++sub){
          int mt = 2*ch + sub;
          f4v acc = {0.f,0.f,0.f,0.f};
          #pragma unroll
          for(int c=0;c<8;++c){
            int arow = mt*16 + ll;
            u32 koff = c*16 + (hl&1)*8;
            s8v A1 = *(const s8v*)((hl<2?Uh:Um) + xbh(arow, koff));
            s8v lf = *(const s8v*)((const u16*)myl + arow*128 + koff);
            s8v hf = *(const s8v*)(Uh + xbh(arow, koff));
            s8v A2 = sel8(hl<2, lf, hf);
            s8v B3 = sel8(hl<2, Bh[c], Blm[c]);
            acc = MFMA32(A1, Bh[c], acc);
            acc = MFMA32(A1, Blm[c], acc);
            acc = MFMA32(A2, B3, acc);
          }
          #pragma unroll
          for(int i=0;i<4;++i)
            *(float*)(SX + xf32(sub*16 + hl*4 + i, w*16 + ll)) = acc[i];
        }
        __syncthreads();
        for(int rr=0; rr<4; ++rr){
          int lr = w*4 + rr; int t = ch*32 + lr;
          float2 pp = *(const float2*)(SX + xf32(lr, 2*lane));
          float v[2] = {pp.x, pp.y};
          f_expmap0<2>(v);
          float eb[2];
          if(m==0){ eb[0]=ebq[0]; eb[1]=ebq[1]; }
          else if(m==1){ eb[0]=ebk[0]; eb[1]=ebk[1]; }
          else { eb[0]=ebv[0]; eb[1]=ebv[1]; }
          f_mobius_add<2>(v, eb);
          f_projx<2>(v);
          f_logmap0<2>(v);
          if(m==0){
            float2 o2; o2.x=v[0]; o2.y=v[1];
            *(float2*)(spare + t*DD + 2*lane) = o2;            // Q f32
          } else if(m==1){
            *(float*)(R2 + xf32(t, 2*lane))   = v[0];          // K f32
            *(float*)(R2 + xf32(t, 2*lane+1)) = v[1];
          } else {
            own[(2*lane)*DD + t]   = v[0];                     // V^T f32 (scatter)
            own[(2*lane+1)*DD + t] = v[1];
          }
        }
        __syncthreads();
      }
    }

    // ---- P3: attention. P tile f32 over U region; ctx overwrites K slices in R2.
    for(int h=0; h<HH; ++h){
      { // cooperative 3c pre-split of K head-slice into SX: [3][128][24-pad] bf16
        int tok = tid & 127, dq = tid >> 7;
        float4 vv = *(const float4*)(R2 + xf32(tok, h*16 + dq*4));
        u32 H0,M0,L0,H1,M1,L1;
        split2(vv.x,vv.y,H0,M0,L0); split2(vv.z,vv.w,H1,M1,L1);
        u32 o = (u32)tok*48u + (u32)dq*8u;
        *(u32*)(SX + 0*6144 + o) = H0; *(u32*)(SX + 0*6144 + o + 4) = H1;
        *(u32*)(SX + 1*6144 + o) = M0; *(u32*)(SX + 1*6144 + o + 4) = M1;
        *(u32*)(SX + 2*6144 + o) = L0; *(u32*)(SX + 2*6144 + o + 4) = L1;
      }
      __syncthreads();
      // QK^T: A = own 16 q-rows (from spare slab, split on the fly)
      float qa[8];
      {
        float4 q0 = *(const float4*)(spare + (w*16+ll)*DD + h*16 + (hl&1)*8);
        float4 q1 = *(const float4*)(spare + (w*16+ll)*DD + h*16 + (hl&1)*8 + 4);
        qa[0]=q0.x; qa[1]=q0.y; qa[2]=q0.z; qa[3]=q0.w;
        qa[4]=q1.x; qa[5]=q1.y; qa[6]=q1.z; qa[7]=q1.w;
      }
      s8v QH,QM,QL; split8(qa, QH,QM,QL);
      s8v qA1 = sel8(hl<2, QH, QM);
      s8v qA2 = sel8(hl<2, QL, QH);
      f4v sc[8];
      #pragma unroll
      for(int nt=0;nt<8;++nt){
        u32 o = (u32)(nt*16+ll)*48u + (u32)(hl&1)*16u;
        s8v B1 = *(const s8v*)(SX + 0*6144 + o);
        s8v B2 = *(const s8v*)(SX + (hl<2?2:1)*6144 + o);
        s8v B3 = sel8(hl<2, B1, B2);
        f4v z = {0.f,0.f,0.f,0.f};
        z = MFMA32(qA1, B1, z);
        z = MFMA32(qA1, B2, z);
        z = MFMA32(qA2, B3, z);
        sc[nt] = z;
      }
      __syncthreads();   // all K-slice reads done (slice reuse + ctx-write safety)
      // softmax (regs) -> P f32 tile @ U region
      #pragma unroll
      for(int i=0;i<4;++i){
        float p8[8]; float mx = -3e38f;
        #pragma unroll
        for(int nt=0;nt<8;++nt){ p8[nt] = sc[nt][i]*0.25f + mb_reg[nt]; mx = fmaxf(mx, p8[nt]); }
        #pragma unroll
        for(int o=1;o<16;o<<=1) mx = fmaxf(mx, __shfl_xor(mx, o, 64));
        float dn = 0.f;
        #pragma unroll
        for(int nt=0;nt<8;++nt){ p8[nt] = expf(p8[nt]-mx); dn += p8[nt]; }
        #pragma unroll
        for(int o=1;o<16;o<<=1) dn += __shfl_xor(dn, o, 64);
        float inv = 1.f/dn;
        #pragma unroll
        for(int nt=0;nt<8;++nt)
          *(float*)(LB + xf32(w*16 + hl*4 + i, nt*16 + ll)) = p8[nt]*inv;
      }
      // PV: A = P own rows (on-the-fly split), B = V^T f32 from own slab (on-the-fly split)
      f4v ca = {0.f,0.f,0.f,0.f};
      #pragma unroll
      for(int c=0;c<8;++c){
        float pa[8];
        {
          float4 p0 = *(const float4*)(LB + xf32(w*16+ll, c*16 + (hl&1)*8));
          float4 p1 = *(const float4*)(LB + xf32(w*16+ll, c*16 + (hl&1)*8 + 4));
          pa[0]=p0.x; pa[1]=p0.y; pa[2]=p0.z; pa[3]=p0.w;
          pa[4]=p1.x; pa[5]=p1.y; pa[6]=p1.z; pa[7]=p1.w;
        }
        s8v PH,PM,PL; split8(pa, PH,PM,PL);
        s8v pA1 = sel8(hl<2, PH, PM);
        s8v pA2 = sel8(hl<2, PL, PH);
        float va[8];
        {
          const float* vp = own + (h*16+ll)*DD + c*16 + (hl&1)*8;
          float4 v0 = *(const float4*)(vp);
          float4 v1 = *(const float4*)(vp + 4);
          va[0]=v0.x; va[1]=v0.y; va[2]=v0.z; va[3]=v0.w;
          va[4]=v1.x; va[5]=v1.y; va[6]=v1.z; va[7]=v1.w;
        }
        s8v VH,VM,VL; split8(va, VH,VM,VL);
        s8v vB2 = sel8(hl<2, VL, VM);
        s8v vB3 = sel8(hl<2, VH, VM);
        ca = MFMA32(pA1, VH, ca);
        ca = MFMA32(pA1, vB2, ca);
        ca = MFMA32(pA2, vB3, ca);
      }
      #pragma unroll
      for(int i=0;i<4;++i)
        *(float*)(R2 + xf32(w*16 + hl*4 + i, h*16 + ll)) = ca[i];   // ctx slice h
    }
    __syncthreads();

    // ---- P4a: u_o = logmap0(expmap0(ctx)) -> Uh/Um/myl (3c)
    for(int r=0;r<16;++r){
      int t = w*16 + r;
      float v[2];
      v[0] = *(const float*)(R2 + xf32(t, 2*lane));
      v[1] = *(const float*)(R2 + xf32(t, 2*lane+1));
      f_expmap0<2>(v);
      f_logmap0<2>(v);
      u32 H,M,L; split2(v[0],v[1],H,M,L);
      *(u32*)(Uh + xbh(t, 2*lane)) = H;
      *(u32*)(Um + xbh(t, 2*lane)) = M;
      ((u32*)myl)[t*64 + lane] = L;
    }
    __syncthreads();

    // ---- P4b/P4c: Wo matvec + attn-out chain, residual -> x1(own), LN2 chain -> u2 (3c)
    {
      const u32 tb = 196608u + (u32)e*16384u;
      s8v Bh[8], Blm[8];
      {
        int nrow = w*16 + ll;
        #pragma unroll
        for(int c=0;c<8;++c){
          u32 koff = c*16 + (hl&1)*8;
          Bh[c]  = *(const s8v*)(wsp + 0*NW3 + tb + nrow*128 + koff);
          Blm[c] = *(const s8v*)(wsp + (hl<2?2:1)*NW3 + tb + nrow*128 + koff);
        }
      }
      for(int ch=0; ch<4; ++ch){
        #pragma unroll
        for(int sub=0; sub<2; ++sub){
          int mt = 2*ch + sub;
          f4v acc = {0.f,0.f,0.f,0.f};
          #pragma unroll
          for(int c=0;c<8;++c){
            int arow = mt*16 + ll;
            u32 koff = c*16 + (hl&1)*8;
            s8v A1 = *(const s8v*)((hl<2?Uh:Um) + xbh(arow, koff));
            s8v lf = *(const s8v*)((const u16*)myl + arow*128 + koff);
            s8v hf = *(const s8v*)(Uh + xbh(arow, koff));
            s8v A2 = sel8(hl<2, lf, hf);
            s8v B3 = sel8(hl<2, Bh[c], Blm[c]);
            acc = MFMA32(A1, Bh[c], acc);
            acc = MFMA32(A1, Blm[c], acc);
            acc = MFMA32(A2, B3, acc);
          }
          #pragma unroll
          for(int i=0;i<4;++i)
            *(float*)(SX + xf32(sub*16 + hl*4 + i, w*16 + ll)) = acc[i];
        }
        __syncthreads();
        for(int rr=0; rr<4; ++rr){
          int lr = w*4 + rr; int t = ch*32 + lr;
          float2 pp = *(const float2*)(SX + xf32(lr, 2*lane));
          float v[2] = {pp.x, pp.y};
          f_expmap0<2>(v);
          f_mobius_add<2>(v, ebo);
          f_projx<2>(v);              // man_linear's projx
          f_projx<2>(v);              // _expert's projx(_mha(...))
          float2 rr2 = *(const float2*)(X + t*DD + 2*lane);
          float res[2] = {rr2.x, rr2.y};
          f_mobius_add<2>(v, res);
          f_projx<2>(v);              // x1
          float2 xo; xo.x=v[0]; xo.y=v[1];
          *(float2*)(own + t*DD + 2*lane) = xo;   // V^T dead; own slab now holds x1
          f_logmap0<2>(v);
          f_layernorm<2>(v, g2, b2);
          f_expmap0<2>(v);
          f_projx<2>(v);
          f_logmap0<2>(v);            // u2
          u32 H,M,L; split2(v[0],v[1],H,M,L);
          *(u32*)(Uh + xbh(t, 2*lane)) = H;
          *(u32*)(Um + xbh(t, 2*lane)) = M;
          ((u32*)myl)[t*64 + lane] = L;
        }
        __syncthreads();
      }
    }

    // ---- P5: FFN in 16-token chunks. FR f32 @ R2[0,32K); HID3 @ HB; fc2 raw @ C2.
    for(int tc=0; tc<8; ++tc){
      // fc1 matvec
      {
        f4v fa[4];
        #pragma unroll
        for(int n4=0;n4<4;++n4){ fa[n4][0]=0.f; fa[n4][1]=0.f; fa[n4][2]=0.f; fa[n4][3]=0.f; }
        #pragma unroll
        for(int c=0;c<8;++c){
          int arow = tc*16 + ll;
          u32 koff = c*16 + (hl&1)*8;
          s8v A1 = *(const s8v*)((hl<2?Uh:Um) + xbh(arow, koff));
          s8v lf = *(const s8v*)((const u16*)myl + arow*128 + koff);
          s8v hf = *(const s8v*)(Uh + xbh(arow, koff));
          s8v A2 = sel8(hl<2, lf, hf);
          #pragma unroll
          for(int n4=0;n4<4;++n4){
            u32 nrow = (u32)((w*4+n4)*16 + ll);
            s8v B1 = *(const s8v*)(wsp + 0*NW3 + 262144u + (u32)e*65536u + nrow*128 + koff);
            s8v B2 = *(const s8v*)(wsp + (hl<2?2:1)*NW3 + 262144u + (u32)e*65536u + nrow*128 + koff);
            s8v B3 = sel8(hl<2, B1, B2);
            fa[n4] = MFMA32(A1, B1, fa[n4]);
            fa[n4] = MFMA32(A1, B2, fa[n4]);
            fa[n4] = MFMA32(A2, B3, fa[n4]);
          }
        }
        #pragma unroll
        for(int n4=0;n4<4;++n4)
          #pragma unroll
          for(int i=0;i<4;++i)
            *(float*)(R2 + xfr_(hl*4+i, (w*4+n4)*16 + ll)) = fa[n4][i];
      }
      __syncthreads();
      // fc1 post -> HID3 (3c planar)
      for(int rr=0; rr<2; ++rr){
        int lr = w*2 + rr;
        float v[8];
        #pragma unroll
        for(int j=0;j<4;++j){
          float2 pp = *(const float2*)(R2 + xfr_(lr, 2*lane + 128*j));
          v[2*j]=pp.x; v[2*j+1]=pp.y;
        }
        f_expmap0<8>(v);
        f_mobius_add<8>(v, ebf1);
        f_projx<8>(v);            // man_linear projx
        f_logmap0<8>(v);
        #pragma unroll
        for(int i=0;i<8;++i) v[i] = fmaxf(v[i], 0.f);
        f_expmap0<8>(v);          // mob_relu
        f_projx<8>(v);            // h = projx(...)
        f_logmap0<8>(v);          // u3
        #pragma unroll
        for(int j=0;j<4;++j){
          u32 H,M,L; split2(v[2*j], v[2*j+1], H,M,L);
          *(u32*)(HB + 0*16384 + xhid(lr, 2*lane + 128*j)) = H;
          *(u32*)(HB + 1*16384 + xhid(lr, 2*lane + 128*j)) = M;
          *(u32*)(HB + 2*16384 + xhid(lr, 2*lane + 128*j)) = L;
        }
      }
      __syncthreads();
      // fc2 matvec (K=512)
      {
        f4v ga = {0.f,0.f,0.f,0.f};
        #pragma unroll
        for(int c=0;c<32;++c){
          u32 koff = c*16 + (hl&1)*8;
          s8v A1 = *(const s8v*)(HB + (hl<2?0:1)*16384 + xhid(ll, koff));
          s8v lf = *(const s8v*)(HB + 2*16384 + xhid(ll, koff));
          s8v hf = *(const s8v*)(HB + 0*16384 + xhid(ll, koff));
          s8v A2 = sel8(hl<2, lf, hf);
          u32 nrow = (u32)(w*16 + ll);
          s8v B1 = *(const s8v*)(wsp + 0*NW3 + 524288u + (u32)e*65536u + nrow*512 + koff);
          s8v B2 = *(const s8v*)(wsp + (hl<2?2:1)*NW3 + 524288u + (u32)e*65536u + nrow*512 + koff);
          s8v B3 = sel8(hl<2, B1, B2);
          ga = MFMA32(A1, B1, ga);
          ga = MFMA32(A1, B2, ga);
          ga = MFMA32(A2, B3, ga);
        }
        #pragma unroll
        for(int i=0;i<4;++i)
          *(float*)(C2 + xf32(hl*4+i, w*16 + ll)) = ga[i];
      }
      __syncthreads();
      // fc2 post + residual + final store (own slab row, overwrites x1 row)
      for(int rr=0; rr<2; ++rr){
        int lr = w*2 + rr; int gt = tc*16 + lr;
        float2 pp; pp.x = *(const float*)(C2 + xf32(lr, 2*lane));
        pp.y = *(const float*)(C2 + xf32(lr, 2*lane+1));
        float v[2] = {pp.x, pp.y};
        f_expmap0<2>(v);
        f_mobius_add<2>(v, ebf2);
        f_projx<2>(v);            // man_linear projx
        f_logmap0<2>(v);
        v[0]=fmaxf(v[0],0.f); v[1]=fmaxf(v[1],0.f);
        f_expmap0<2>(v);          // mob_relu (no projx per reference)
        float2 xx = *(const float2*)(own + gt*DD + 2*lane);
        float x1v[2] = {xx.x, xx.y};
        f_mobius_add<2>(v, x1v);
        f_projx<2>(v);
        float2 o2; o2.x=v[0]; o2.y=v[1];
        *(float2*)(own + gt*DD + 2*lane) = o2;
      }
      __syncthreads();
    }

    // re-zero spare slab (was Q scratch)
    {
      float4 z4 = {0.f,0.f,0.f,0.f};
      for(int i=tid; i<4096; i+=512) *(float4*)(spare + 4*i) = z4;
    }
  }
}

// ===================== scalar fallback (bf16 wire / tiny-ws f32) =====================
template<typename T>
__global__ __launch_bounds__(256)
void moe_kernel(const int* __restrict__ flag,
                const T* __restrict__ feat, const int* __restrict__ eidx,
                const float* __restrict__ mbias,
                const T* __restrict__ ln1g, const T* __restrict__ ln1b,
                const T* __restrict__ ln2g, const T* __restrict__ ln2b,
                const T* __restrict__ wq, const T* __restrict__ bq,
                const T* __restrict__ wk, const T* __restrict__ bk_,
                const T* __restrict__ wv, const T* __restrict__ bv,
                const T* __restrict__ wo, const T* __restrict__ bo,
                const T* __restrict__ f1w, const T* __restrict__ f1b,
                const T* __restrict__ f2w, const T* __restrict__ f2b,
                T* __restrict__ out, float* __restrict__ ws, int ntask)
{
  const int want = (sizeof(T)==4) ? 1 : 0;
  if(*flag != want) return;

  __shared__ float U[SS*DD];
  const int tid  = threadIdx.x;
  const int lane = tid & 63;
  const int wid  = tid >> 6;
  float* T0 = ws + (size_t)blockIdx.x * (4*SS*DD);
  float* T1 = T0 + SS*DD;
  float* T2 = T1 + SS*DD;
  float* T3 = T2 + SS*DD;

  for(int task = blockIdx.x; task < ntask; task += gridDim.x){
    __syncthreads();
    const int b = task >> 1;
    const int e = eidx[b*KK + (task & 1)];
    const T* X = feat + (size_t)task * (SS*DD);

    for(int r=0;r<32;++r){
      int t = wid*32 + r;
      float v[2];
      v[0]=ldv(&X[t*DD+lane]); v[1]=ldv(&X[t*DD+lane+64]);
      f_logmap0<2>(v);
      float g[2], bb[2];
      g[0]=ldv(&ln1g[e*DD+lane]);  g[1]=ldv(&ln1g[e*DD+lane+64]);
      bb[0]=ldv(&ln1b[e*DD+lane]); bb[1]=ldv(&ln1b[e*DD+lane+64]);
      f_layernorm<2>(v,g,bb);
      f_expmap0<2>(v);
      f_logmap0<2>(v);
      U[t*DD+lane]=v[0]; U[t*DD+lane+64]=v[1];
    }
    __syncthreads();

    {
      int j = tid & 127, tg = tid >> 7;
      for(int m=0;m<3;++m){
        const T* Wm = (m==0?wq : m==1?wk : wv) + (size_t)e*DD*DD + (size_t)j*DD;
        float* Ym = (m==0?T0 : m==1?T1 : T2);
        float w[128];
        loadrow(Wm, w);
        for(int tt=0;tt<64;++tt){
          int t = tg*64+tt;
          Ym[t*DD+j] = dotrow(w, &U[t*DD]);
        }
      }
    }
    __syncthreads();

    for(int m=0;m<3;++m){
      const T* bias = (m==0?bq : m==1?bk_ : bv) + e*DD;
      float* Y = (m==0?T0 : m==1?T1 : T2);
      for(int r=0;r<32;++r){
        int t = wid*32+r;
        float v[2]; v[0]=Y[t*DD+lane]; v[1]=Y[t*DD+lane+64];
        f_expmap0<2>(v);
        float ebv2[2]; ebv2[0]=ldv(&bias[lane]); ebv2[1]=ldv(&bias[lane+64]);
        f_expmap0<2>(ebv2);
        f_mobius_add<2>(v, ebv2);
        f_projx<2>(v);
        f_logmap0<2>(v);
        Y[t*DD+lane]=v[0]; Y[t*DD+lane+64]=v[1];
      }
    }
    __syncthreads();

    {
      const float* mb = mbias + b*SS;
      for(int h=0; h<HH; ++h){
        for(int r=0;r<32;++r){
          int t = wid*32+r;
          float q16[16];
          #pragma unroll
          for(int i=0;i<16;++i) q16[i] = T0[t*DD + h*HDIM + i];
          int k0 = lane, k1 = lane+64;
          float s0=0.f, s1=0.f;
          #pragma unroll
          for(int i=0;i<16;++i){
            s0 += q16[i]*T1[k0*DD + h*HDIM + i];
            s1 += q16[i]*T1[k1*DD + h*HDIM + i];
          }
          s0 = s0*0.25f + mb[k0];
          s1 = s1*0.25f + mb[k1];
          float mx = wmax(fmaxf(s0,s1));
          float p0 = expf(s0-mx), p1 = expf(s1-mx);
          float dn = wsum(p0+p1);
          p0 /= dn; p1 /= dn;
          float part[16];
          #pragma unroll
          for(int i=0;i<16;++i)
            part[i] = p0*T2[k0*DD+h*HDIM+i] + p1*T2[k1*DD+h*HDIM+i];
          #pragma unroll
          for(int off=1; off<64; off<<=1){
            #pragma unroll
            for(int i=0;i<16;++i) part[i] += __shfl_xor(part[i], off, 64);
          }
          if(lane==0){
            #pragma unroll
            for(int i=0;i<16;++i) T0[t*DD + h*HDIM + i] = part[i];
          }
        }
      }
    }
    __syncthreads();

    for(int r=0;r<32;++r){
      int t=wid*32+r;
      float v[2]; v[0]=T0[t*DD+lane]; v[1]=T0[t*DD+lane+64];
      f_expmap0<2>(v);
      f_logmap0<2>(v);
      U[t*DD+lane]=v[0]; U[t*DD+lane+64]=v[1];
    }
    __syncthreads();

    {
      int j=tid&127, tg=tid>>7;
      float w[128];
      loadrow(wo + (size_t)e*DD*DD + (size_t)j*DD, w);
      for(int tt=0;tt<64;++tt){
        int t=tg*64+tt;
        T1[t*DD+j] = dotrow(w, &U[t*DD]);
      }
    }
    __syncthreads();

    for(int r=0;r<32;++r){
      int t=wid*32+r;
      float v[2]; v[0]=T1[t*DD+lane]; v[1]=T1[t*DD+lane+64];
      f_expmap0<2>(v);
      float ebv2[2]; ebv2[0]=ldv(&bo[e*DD+lane]); ebv2[1]=ldv(&bo[e*DD+lane+64]);
      f_expmap0<2>(ebv2);
      f_mobius_add<2>(v, ebv2);
      f_projx<2>(v);
      f_projx<2>(v);
      float res[2]; res[0]=ldv(&X[t*DD+lane]); res[1]=ldv(&X[t*DD+lane+64]);
      f_mobius_add<2>(v, res);
      f_projx<2>(v);
      T3[t*DD+lane]=v[0]; T3[t*DD+lane+64]=v[1];
      f_logmap0<2>(v);
      float g2[2], b2[2];
      g2[0]=ldv(&ln2g[e*DD+lane]); g2[1]=ldv(&ln2g[e*DD+lane+64]);
      b2[0]=ldv(&ln2b[e*DD+lane]); b2[1]=ldv(&ln2b[e*DD+lane+64]);
      f_layernorm<2>(v,g2,b2);
      f_expmap0<2>(v);
      f_projx<2>(v);
      f_logmap0<2>(v);
      U[t*DD+lane]=v[0]; U[t*DD+lane+64]=v[1];
    }
    __syncthreads();

    float* HID = T0;
    for(int tc=0; tc<2; ++tc){
      for(int pass=0;pass<2;++pass){
        int f = pass*256 + tid;
        float w[128];
        loadrow(f1w + (size_t)e*FF*DD + (size_t)f*DD, w);
        for(int tt=0;tt<64;++tt){
          HID[tt*FF+f] = dotrow(w, &U[(tc*64+tt)*DD]);
        }
      }
      __syncthreads();
      for(int r=0;r<16;++r){
        int t = wid*16+r;
        float v[8];
        #pragma unroll
        for(int i=0;i<8;++i) v[i]=HID[t*FF+lane+64*i];
        f_expmap0<8>(v);
        float ebv8[8];
        #pragma unroll
        for(int i=0;i<8;++i) ebv8[i]=ldv(&f1b[e*FF+lane+64*i]);
        f_expmap0<8>(ebv8);
        f_mobius_add<8>(v, ebv8);
        f_projx<8>(v);
        f_logmap0<8>(v);
        #pragma unroll
        for(int i=0;i<8;++i) v[i]=fmaxf(v[i],0.f);
        f_expmap0<8>(v);
        f_projx<8>(v);
        f_logmap0<8>(v);
        #pragma unroll
        for(int i=0;i<8;++i) HID[t*FF+lane+64*i]=v[i];
      }
      __syncthreads();
      {
        int j=tid&127, tg=tid>>7;
        for(int fc=0;fc<4;++fc){
          float w[128];
          loadrow(f2w + (size_t)e*DD*FF + (size_t)j*FF + fc*128, w);
          for(int tt=0;tt<32;++tt){
            int t=tg*32+tt;
            float acc = dotrow(w, HID + t*FF + fc*128);
            if(fc==0) T2[t*DD+j]=acc; else T2[t*DD+j]+=acc;
          }
        }
      }
      __syncthreads();
      for(int r=0;r<16;++r){
        int t=wid*16+r; int gt = tc*64+t;
        float v[2]; v[0]=T2[t*DD+lane]; v[1]=T2[t*DD+lane+64];
        f_expmap0<2>(v);
        float ebv2[2]; ebv2[0]=ldv(&f2b[e*DD+lane]); ebv2[1]=ldv(&f2b[e*DD+lane+64]);
        f_expmap0<2>(ebv2);
        f_mobius_add<2>(v, ebv2);
        f_projx<2>(v);
        f_logmap0<2>(v);
        v[0]=fmaxf(v[0],0.f); v[1]=fmaxf(v[1],0.f);
        f_expmap0<2>(v);
        float x1v[2]; x1v[0]=T3[gt*DD+lane]; x1v[1]=T3[gt*DD+lane+64];
        f_mobius_add<2>(v, x1v);
        f_projx<2>(v);
        T* op = out + ((size_t)(b*EE+e)*SS + gt)*DD;
        stv(&op[lane],    v[0]);
        stv(&op[lane+64], v[1]);
      }
      __syncthreads();
    }
  }
}

extern "C" void kernel_launch(void* const* d_in, const int* in_sizes, int n_in,
                              void* d_out, int out_size, void* d_ws, size_t ws_size,
                              hipStream_t stream){
  const void* feat = d_in[0];
  const int* eidx = (const int*)d_in[1];
  const unsigned char* pmask = (const unsigned char*)d_in[2];
  float* ws = (float*)d_ws;

  // ws layout (f32 units): [0..16) flag, [16..16+BB*SS) mbias,
  // then (new path) wsplit 3 bf16 planes (1179648 f32), then per-block u-l planes (8192 f32 each)
  int* flag = (int*)ws;
  float* mbias = ws + 16;
  float* tiles = ws + 16 + BB*SS;              // old-path tiles (aliases wsplit region; exclusive)
  u16* wsp = (u16*)(ws + 16 + BB*SS);
  const size_t WSP_F32 = (size_t)(3*NW3)/2;    // 1179648
  float* wsl = ws + 16 + BB*SS + WSP_F32;

  long wsf = (long)(ws_size/sizeof(float));
  long avail_old = wsf - (16 + BB*SS);
  long remain = wsf - (long)(16 + BB*SS) - (long)WSP_F32;

  // old-path grid (bf16-wire scalar kernel; also f32 fallback if ws too small)
  int G = (int)(avail_old / (long)(4*SS*DD));
  if(G > NTASK) G = NTASK;
  if(G < 1) G = 1;
  // new-path grid
  int G2 = (int)(remain / 8192);
  if(G2 > 256) G2 = 256;
  bool newpath = (G2 >= 1);

  prep_kernel<<<1,256,0,stream>>>((const u16*)feat, pmask, mbias, flag);
  zero_nr<u16>  <<<2048,256,0,stream>>>(flag, eidx, (u16*)d_out);
  zero_nr<float><<<2048,256,0,stream>>>(flag, eidx, (float*)d_out);

  if(newpath){
    wsplit_kernel<<<(NW3+255)/256,256,0,stream>>>(flag,
      (const float*)d_in[7], (const float*)d_in[9], (const float*)d_in[11], (const float*)d_in[13],
      (const float*)d_in[15], (const float*)d_in[17], wsp);
    moe_f32<<<G2,512,0,stream>>>(flag, (const float*)d_in[0], eidx, mbias,
      (const float*)d_in[3], (const float*)d_in[4], (const float*)d_in[5], (const float*)d_in[6],
      (const float*)d_in[8], (const float*)d_in[10], (const float*)d_in[12], (const float*)d_in[14],
      (const float*)d_in[16], (const float*)d_in[18],
      wsp, (float*)d_out, wsl, NTASK);
  }

  #define ARGS(T_) flag, (const T_*)d_in[0], eidx, mbias, \
    (const T_*)d_in[3], (const T_*)d_in[4], (const T_*)d_in[5], (const T_*)d_in[6], \
    (const T_*)d_in[7], (const T_*)d_in[8], (const T_*)d_in[9], (const T_*)d_in[10], \
    (const T_*)d_in[11], (const T_*)d_in[12], (const T_*)d_in[13], (const T_*)d_in[14], \
    (const T_*)d_in[15], (const T_*)d_in[16], (const T_*)d_in[17], (const T_*)d_in[18], \
    (T_*)d_out, tiles, NTASK
  moe_kernel<u16><<<G,256,0,stream>>>(ARGS(u16));
  if(!newpath){
    moe_kernel<float><<<G,256,0,stream>>>(ARGS(float));
  }
  #undef ARGS
}